// Round 8
// baseline (880.369 us; speedup 1.0000x reference)
//
#include <hip/hip_runtime.h>
#include <math.h>

#define N_NODES 131072
#define G_GRP   512
#define TPB     256          // 64 nodes/block, 4 lanes per node (u-split)
#define NPB     64           // nodes per block
#define SPAN    32

// d_ws float offsets
#define ACC_OFF   0        // 3072 floats (512 groups * 6)
#define PG1_OFF   4096     // 8192 floats: [u4][j][du]  (Wg1 packed)
#define PC_OFF    12288    // 6144 floats: [j][out=c*16+h] (Wg2 * wpost combos)
#define CB_OFF    18432    // 96 floats   (bg2 * wpost combos)
#define P0_OFF    18560    // 2048 floats: [u4][h][du] (W0)
#define P1_OFF    20608    // 1024 floats: [u4][h][du] (W1)
#define P2_OFF    21632    // 512 floats : [u4][h][du] (W2)
#define BG1_OFF   22144    // 64 floats

__global__ __launch_bounds__(256) void repack_kernel(
    const float* __restrict__ W0, const float* __restrict__ W1,
    const float* __restrict__ W2, const float* __restrict__ Wg1,
    const float* __restrict__ bg1, const float* __restrict__ Wg2,
    const float* __restrict__ bg2, const float* __restrict__ wp0,
    const float* __restrict__ wp2, float* __restrict__ ws)
{
  int i = blockIdx.x * 256 + threadIdx.x;
  if (i < 8192) {               // PG1[u4*256 + j*4 + du] = Wg1[(4u4+du)][j]
    int du = i & 3, j = (i >> 2) & 63, u4 = i >> 8;
    ws[PG1_OFF + i] = Wg1[(u4 * 4 + du) * 64 + j];
  }
  if (i < 6144) {               // PC[j*96 + out]
    int out = i % 96, j = i / 96;
    int cidx = out >> 4, h = out & 15;
    const float* row = Wg2 + j * 144;
    float v;
    switch (cidx) {
      case 0:  v = wp0[0] * row[h];        break;   // w[:,0] -> o0 s^2
      case 1:  v = wp0[1] * row[32 + h];   break;   // w[:,2] -> o0 |v|^2
      case 2:  v = wp0[2] * row[96 + h];   break;   // w[:,6] -> o0 |t|^2
      case 3:  v = wp2[0] * row[16 + h] + wp2[2] * row[80 + h]; break; // s*t5
      case 4:  v = wp2[1] * row[64 + h];   break;   // vv5
      default: v = wp2[3] * row[128 + h];  break;   // tt5
    }
    ws[PC_OFF + i] = v;
  }
  if (i < 2048) {
    int du = i & 3, h = (i >> 2) & 15, u4 = i >> 6;
    ws[P0_OFF + i] = W0[(u4 * 4 + du) * 16 + h];
  }
  if (i < 1024) {
    int du = i & 3, h = (i >> 2) & 15, u4 = i >> 6;
    ws[P1_OFF + i] = W1[(u4 * 4 + du) * 16 + h];
  }
  if (i < 512) {
    int du = i & 3, h = (i >> 2) & 15, u4 = i >> 6;
    ws[P2_OFF + i] = W2[(u4 * 4 + du) * 16 + h];
  }
  if (i < 96) {
    int cidx = i >> 4, h = i & 15;
    float v;
    switch (cidx) {
      case 0:  v = wp0[0] * bg2[h];        break;
      case 1:  v = wp0[1] * bg2[32 + h];   break;
      case 2:  v = wp0[2] * bg2[96 + h];   break;
      case 3:  v = wp2[0] * bg2[16 + h] + wp2[2] * bg2[80 + h]; break;
      case 4:  v = wp2[1] * bg2[64 + h];   break;
      default: v = wp2[3] * bg2[128 + h];  break;
    }
    ws[CB_OFF + i] = v;
  }
  if (i < 64) ws[BG1_OFF + i] = bg1[i];
}

// Reduce-scatter a 16-wide per-lane partial vector over the 4-lane node group.
// Lane l (=tid&3) ends with fully-summed h = 4*l + i in out[i], i=0..3.
// Non-divergent: both candidates computed by all lanes, cndmask select.
__device__ __forceinline__ void rs16(const float* __restrict__ p, int l,
                                     float* __restrict__ out)
{
  float q[8];
#pragma unroll
  for (int i = 0; i < 8; ++i) {
    float a = p[i]     + __shfl_xor(p[i],     2);
    float b = p[i + 8] + __shfl_xor(p[i + 8], 2);
    q[i] = (l & 2) ? b : a;
  }
#pragma unroll
  for (int i = 0; i < 4; ++i) {
    float a = q[i]     + __shfl_xor(q[i],     1);
    float b = q[i + 4] + __shfl_xor(q[i + 4], 1);
    out[i] = (l & 1) ? b : a;
  }
}

__global__ __launch_bounds__(TPB, 1) void node_kernel(
    const float* __restrict__ xsc, const float* __restrict__ xsp,
    const int* __restrict__ bidx, float* __restrict__ ws)
{
  __shared__ float accL[SPAN * 6];
  const int tid  = threadIdx.x;
  const int nl   = tid >> 2;          // node-local 0..63
  const int l    = tid & 3;           // lane within node group (u-quarter)
  const int node = blockIdx.x * NPB + nl;

  for (int i = tid; i < SPAN * 6; i += TPB) accL[i] = 0.f;
  __syncthreads();

  const float SQ2 = 1.41421356237f;
  const float I2  = 0.70710678118f;
  const float I6  = 0.40824829046f;

  // ---------- gate1: partial over u-quarter, quad-allreduce, silu ----------
  float hid[64];
#pragma unroll
  for (int j = 0; j < 64; ++j) hid[j] = 0.f;
  {
    const float4* __restrict__ xp = (const float4*)(xsc + (size_t)node * 128);
    const float4* __restrict__ wg = (const float4*)(ws + PG1_OFF);
    for (int i = 0; i < 8; ++i) {
      int u4 = 8 * l + i;
      float4 x4 = xp[u4];
      const float4* __restrict__ wrow = wg + (u4 << 6);
#pragma unroll
      for (int j = 0; j < 64; ++j) {
        float4 w = wrow[j];
        hid[j] = fmaf(x4.x, w.x, fmaf(x4.y, w.y, fmaf(x4.z, w.z, fmaf(x4.w, w.w, hid[j]))));
      }
    }
#pragma unroll
    for (int j = 0; j < 64; ++j) hid[j] += __shfl_xor(hid[j], 1);
#pragma unroll
    for (int j = 0; j < 64; ++j) hid[j] += __shfl_xor(hid[j], 2);
    const float* __restrict__ BG1 = ws + BG1_OFF;
#pragma unroll
    for (int j = 0; j < 64; ++j) {
      float hh = hid[j] + BG1[j];
      hid[j] = hh / (1.f + __expf(-hh));   // silu
    }
  }

  // ---------- coef: lane owns h = 4l..4l+3 of all 6 groups ----------
  // c[0]=c0(s^2), c[1]=c1(|v|^2), c[2]=c2(|t|^2), c[3]=c3(s*t5), c[4]=c4(vv5), c[5]=c5(tt5)
  float c[6][4];
  {
    const float4* __restrict__ cb4 = (const float4*)(ws + CB_OFF);
#pragma unroll
    for (int g = 0; g < 6; ++g) {
      float4 b = cb4[g * 4 + l];
      c[g][0] = b.x; c[g][1] = b.y; c[g][2] = b.z; c[g][3] = b.w;
    }
    const float4* __restrict__ pc = (const float4*)(ws + PC_OFF);
#pragma unroll 8
    for (int j = 0; j < 64; ++j) {
      float hj = hid[j];
      const float4* __restrict__ row = pc + j * 24;
#pragma unroll
      for (int g = 0; g < 6; ++g) {
        float4 w = row[g * 4 + l];
        c[g][0] = fmaf(hj, w.x, c[g][0]);
        c[g][1] = fmaf(hj, w.y, c[g][1]);
        c[g][2] = fmaf(hj, w.z, c[g][2]);
        c[g][3] = fmaf(hj, w.w, c[g][3]);
      }
    }
  }

  float o0 = 0.f;
  float o2m0 = 0.f, o2m1 = 0.f, o2m2 = 0.f, o2m3 = 0.f, o2m4 = 0.f;

  // ---------- s-phase ----------
  {
    float sp[16];
#pragma unroll
    for (int h = 0; h < 16; ++h) sp[h] = 0.f;
    const float4* __restrict__ xp = (const float4*)(xsp + (size_t)node * 480);
    const float4* __restrict__ p0 = (const float4*)(ws + P0_OFF);
    for (int i = 0; i < 8; ++i) {
      int u4 = 8 * l + i;
      float4 x4 = xp[u4];
      const float4* __restrict__ row = p0 + (u4 << 4);
#pragma unroll
      for (int h = 0; h < 16; ++h) {
        float4 w = row[h];
        sp[h] = fmaf(x4.x, w.x, fmaf(x4.y, w.y, fmaf(x4.z, w.z, fmaf(x4.w, w.w, sp[h]))));
      }
    }
    float sm[4];
    rs16(sp, l, sm);
#pragma unroll
    for (int i = 0; i < 4; ++i) {
      o0 = fmaf(c[0][i] * sm[i], sm[i], o0);   // c0*s^2
      c[3][i] *= sm[i];                        // c3 -> c3*s
    }
  }

  // ---------- v-phase (contiguous chunk, phase-aligned triplets) ----------
  {
    float v0[16], v1[16], v2[16];
#pragma unroll
    for (int h = 0; h < 16; ++h) { v0[h] = 0.f; v1[h] = 0.f; v2[h] = 0.f; }
    const float4* __restrict__ xp = (const float4*)(xsp + (size_t)node * 480 + 128);
    const float4* __restrict__ p1 = (const float4*)(ws + P1_OFF);
    for (int g = 0; g < 4; ++g) {
      int m0 = 12 * l + 3 * g;               // 12l%3==0 -> A,B,C aligned
      float4 A = xp[m0], B = xp[m0 + 1], C = xp[m0 + 2];
      const float4* __restrict__ row = p1 + ((4 * l + g) << 4);
#pragma unroll
      for (int h = 0; h < 16; ++h) {
        float4 w = row[h];
        v0[h] = fmaf(A.x, w.x, v0[h]); v1[h] = fmaf(A.y, w.x, v1[h]); v2[h] = fmaf(A.z, w.x, v2[h]);
        v0[h] = fmaf(A.w, w.y, v0[h]); v1[h] = fmaf(B.x, w.y, v1[h]); v2[h] = fmaf(B.y, w.y, v2[h]);
        v0[h] = fmaf(B.z, w.z, v0[h]); v1[h] = fmaf(B.w, w.z, v1[h]); v2[h] = fmaf(C.x, w.z, v2[h]);
        v0[h] = fmaf(C.y, w.w, v0[h]); v1[h] = fmaf(C.z, w.w, v1[h]); v2[h] = fmaf(C.w, w.w, v2[h]);
      }
    }
    float a4[4], b4[4], d4[4];
    rs16(v0, l, a4);
    rs16(v1, l, b4);
    rs16(v2, l, d4);
#pragma unroll
    for (int i = 0; i < 4; ++i) {
      float a = a4[i], b = b4[i], d = d4[i];
      float nv = fmaf(a, a, fmaf(b, b, d * d));
      o0 = fmaf(c[1][i], nv, o0);                          // c1*|v|^2
      float c4h = c[4][i];
      o2m0 = fmaf(c4h, SQ2 * d * a, o2m0);                 // vv5[0]
      o2m1 = fmaf(c4h, SQ2 * a * b, o2m1);                 // vv5[1]
      o2m2 = fmaf(c4h, (2.f*b*b - d*d - a*a) * I6, o2m2);  // vv5[2]
      o2m3 = fmaf(c4h, SQ2 * b * d, o2m3);                 // vv5[3]
      o2m4 = fmaf(c4h, (d*d - a*a) * I2, o2m4);            // vv5[4]
    }
  }

  // ---------- t-phase (5 m-passes, 16-reg partials) ----------
  {
    float tm[5][4];
    const float* __restrict__ xt = xsp + (size_t)node * 480 + 320;
    const float4* __restrict__ p2 = (const float4*)(ws + P2_OFF);
#pragma unroll
    for (int m = 0; m < 5; ++m) {
      float tp[16];
#pragma unroll
      for (int h = 0; h < 16; ++h) tp[h] = 0.f;
      for (int g = 0; g < 8; ++g) {
        int u = 8 * l + g;
        float xv = xt[u * 5 + m];
        const float4* __restrict__ row = p2 + (u << 4);
#pragma unroll
        for (int h4 = 0; h4 < 4; ++h4) {
          float4 w = row[h4 * 4 + 0];  // NOTE: row is 16 float4s? no: see below
          // placeholder -- replaced by per-h loop
        }
#pragma unroll
        for (int h = 0; h < 16; ++h) {
          // P2 row layout: [u][h][du]; here each u has 16 h x 4 du, but t
          // weights are per (u,h) scalars replicated? No: W2 is (32,16) --
          // P2 stores [u4][h][du] float4 rows; element (u,h) = P2row(u>>2)[h][u&3]
          ;
        }
        // actual accumulation below (see t_accum)
        const float* __restrict__ rowf = (const float*)(p2) + ((u >> 2) << 6);
#pragma unroll
        for (int h = 0; h < 16; ++h)
          tp[h] = fmaf(xv, rowf[h * 4 + (u & 3)], tp[h]);
      }
      rs16(tp, l, tm[m]);
    }
#pragma unroll
    for (int i = 0; i < 4; ++i) {
      float q0 = tm[0][i], q1 = tm[1][i], q2 = tm[2][i], q3 = tm[3][i], q4 = tm[4][i];
      float nt = fmaf(q0,q0, fmaf(q1,q1, fmaf(q2,q2, fmaf(q3,q3, q4*q4))));
      o0 = fmaf(c[2][i], nt, o0);                          // c2*|t|^2
      float c3sh = c[3][i];                                // (c3*s)
      o2m0 = fmaf(c3sh, q0, o2m0);
      o2m1 = fmaf(c3sh, q1, o2m1);
      o2m2 = fmaf(c3sh, q2, o2m2);
      o2m3 = fmaf(c3sh, q3, o2m3);
      o2m4 = fmaf(c3sh, q4, o2m4);
      // T (symmetric traceless) from t5, A = T*T
      float d0 = -q2*I6 - q4*I2;
      float d1 =  2.f*q2*I6;
      float d2 = -q2*I6 + q4*I2;
      float a = q1*I2, b = q0*I2, cc = q3*I2;
      float A00 = fmaf(d0,d0, fmaf(a,a, b*b));
      float A11 = fmaf(a,a, fmaf(d1,d1, cc*cc));
      float A22 = fmaf(b,b, fmaf(cc,cc, d2*d2));
      float A01 = fmaf(a, d0 + d1, b*cc);
      float A02 = fmaf(b, d0 + d2, a*cc);
      float A12 = fmaf(cc, d1 + d2, a*b);
      float c5h = c[5][i];
      o2m0 = fmaf(c5h, SQ2 * A02, o2m0);
      o2m1 = fmaf(c5h, SQ2 * A01, o2m1);
      o2m2 = fmaf(c5h, (2.f*A11 - A22 - A00) * I6, o2m2);
      o2m3 = fmaf(c5h, SQ2 * A12, o2m3);
      o2m4 = fmaf(c5h, (A22 - A00) * I2, o2m4);
    }
  }

  // ---------- combine 4-lane group, then segment accumulate ----------
  o0   += __shfl_xor(o0,   1); o0   += __shfl_xor(o0,   2);
  o2m0 += __shfl_xor(o2m0, 1); o2m0 += __shfl_xor(o2m0, 2);
  o2m1 += __shfl_xor(o2m1, 1); o2m1 += __shfl_xor(o2m1, 2);
  o2m2 += __shfl_xor(o2m2, 1); o2m2 += __shfl_xor(o2m2, 2);
  o2m3 += __shfl_xor(o2m3, 1); o2m3 += __shfl_xor(o2m3, 2);
  o2m4 += __shfl_xor(o2m4, 1); o2m4 += __shfl_xor(o2m4, 2);

  int g = bidx[node];
  int gmin = bidx[blockIdx.x * NPB];
  int rel = g - gmin;
  float* __restrict__ ACC = ws + ACC_OFF;
  if (l == 0) {
    if (rel < SPAN) {
      atomicAdd(&accL[rel*6 + 0], o0);
      atomicAdd(&accL[rel*6 + 1], o2m0);
      atomicAdd(&accL[rel*6 + 2], o2m1);
      atomicAdd(&accL[rel*6 + 3], o2m2);
      atomicAdd(&accL[rel*6 + 4], o2m3);
      atomicAdd(&accL[rel*6 + 5], o2m4);
    } else {
      atomicAdd(&ACC[g*6 + 0], o0);
      atomicAdd(&ACC[g*6 + 1], o2m0);
      atomicAdd(&ACC[g*6 + 2], o2m1);
      atomicAdd(&ACC[g*6 + 3], o2m2);
      atomicAdd(&ACC[g*6 + 4], o2m3);
      atomicAdd(&ACC[g*6 + 5], o2m4);
    }
  }
  __syncthreads();
  for (int i = tid; i < SPAN * 6; i += TPB) {
    float val = accL[i];
    if (val != 0.f) atomicAdd(&ACC[(gmin + i / 6) * 6 + (i % 6)], val);
  }
}

__global__ __launch_bounds__(64) void finalize_kernel(
    const float* __restrict__ ws, float* __restrict__ out)
{
  int g = blockIdx.x * 64 + threadIdx.x;
  if (g >= G_GRP) return;
  const float I2 = 0.70710678118f, I3 = 0.57735026919f, I6 = 0.40824829046f;
  const float* A = ws + ACC_OFF + g * 6;
  float g0 = A[0], q0 = A[1], q1 = A[2], q2 = A[3], q3 = A[4], q4 = A[5];
  float M00 = g0*I3 - q2*I6 - q4*I2;
  float M11 = g0*I3 + 2.f*q2*I6;
  float M22 = g0*I3 - q2*I6 + q4*I2;
  float M01 = q1*I2, M02 = q0*I2, M12 = q3*I2;
  float* o = out + g * 9;
  // out[a][b] = M[p[a]][p[b]], p = {2,0,1}
  o[0] = M22; o[1] = M02; o[2] = M12;
  o[3] = M02; o[4] = M00; o[5] = M01;
  o[6] = M12; o[7] = M01; o[8] = M11;
}

extern "C" void kernel_launch(void* const* d_in, const int* in_sizes, int n_in,
                              void* d_out, int out_size, void* d_ws, size_t ws_size,
                              hipStream_t stream)
{
  const float* xsc = (const float*)d_in[0];   // x_scalar  (N,128)
  const float* xsp = (const float*)d_in[1];   // x_spherical (N,480)
  // d_in[2] = coord (unused)
  const int*   bidx = (const int*)d_in[3];    // batch_index (N,)
  const float* W0  = (const float*)d_in[4];
  const float* W1  = (const float*)d_in[5];
  const float* W2  = (const float*)d_in[6];
  const float* Wg1 = (const float*)d_in[7];
  const float* bg1 = (const float*)d_in[8];
  const float* Wg2 = (const float*)d_in[9];
  const float* bg2 = (const float*)d_in[10];
  const float* wp0 = (const float*)d_in[11];
  const float* wp2 = (const float*)d_in[12];
  float* ws = (float*)d_ws;

  hipMemsetAsync(d_ws, 0, 3072 * sizeof(float), stream);
  repack_kernel<<<32, 256, 0, stream>>>(W0, W1, W2, Wg1, bg1, Wg2, bg2, wp0, wp2, ws);
  node_kernel<<<N_NODES / NPB, TPB, 0, stream>>>(xsc, xsp, bidx, ws);
  finalize_kernel<<<(G_GRP + 63) / 64, 64, 0, stream>>>(ws, (float*)d_out);
}

// Round 9
// 545.659 us; speedup vs baseline: 1.6134x; 1.6134x over previous
//
#include <hip/hip_runtime.h>
#include <math.h>

#define N_NODES 131072
#define G_GRP   512
#define TPB     128          // 64 nodes/block, 2 lanes per node (output-split)
#define NPB     64           // nodes per block
#define SPAN    32

// d_ws float offsets
#define ACC_OFF   0        // 3072 floats (512 groups * 6)
#define PG1_OFF   4096     // 8192 floats: [u4][j][du]  (Wg1 packed)
#define PC_OFF    12288    // 6144 floats: [j][out=c*16+h] (Wg2 * wpost combos)
#define CB_OFF    18432    // 96 floats   (bg2 * wpost combos)
#define P0_OFF    18560    // 2048 floats: [u4][h][du] (W0)
#define P1_OFF    20608    // 1024 floats: [u4][h][du] (W1)
#define P2_OFF    21632    // 512 floats : [u4][h][du] (W2)
#define BG1_OFF   22144    // 64 floats

__global__ __launch_bounds__(256) void repack_kernel(
    const float* __restrict__ W0, const float* __restrict__ W1,
    const float* __restrict__ W2, const float* __restrict__ Wg1,
    const float* __restrict__ bg1, const float* __restrict__ Wg2,
    const float* __restrict__ bg2, const float* __restrict__ wp0,
    const float* __restrict__ wp2, float* __restrict__ ws)
{
  int i = blockIdx.x * 256 + threadIdx.x;
  if (i < 8192) {               // PG1[u4*256 + j*4 + du] = Wg1[(4u4+du)][j]
    int du = i & 3, j = (i >> 2) & 63, u4 = i >> 8;
    ws[PG1_OFF + i] = Wg1[(u4 * 4 + du) * 64 + j];
  }
  if (i < 6144) {               // PC[j*96 + out]
    int out = i % 96, j = i / 96;
    int cidx = out >> 4, h = out & 15;
    const float* row = Wg2 + j * 144;
    float v;
    switch (cidx) {
      case 0:  v = wp0[0] * row[h];        break;   // w[:,0] -> o0 s^2
      case 1:  v = wp0[1] * row[32 + h];   break;   // w[:,2] -> o0 |v|^2
      case 2:  v = wp0[2] * row[96 + h];   break;   // w[:,6] -> o0 |t|^2
      case 3:  v = wp2[0] * row[16 + h] + wp2[2] * row[80 + h]; break; // s*t5
      case 4:  v = wp2[1] * row[64 + h];   break;   // vv5
      default: v = wp2[3] * row[128 + h];  break;   // tt5
    }
    ws[PC_OFF + i] = v;
  }
  if (i < 2048) {
    int du = i & 3, h = (i >> 2) & 15, u4 = i >> 6;
    ws[P0_OFF + i] = W0[(u4 * 4 + du) * 16 + h];
  }
  if (i < 1024) {
    int du = i & 3, h = (i >> 2) & 15, u4 = i >> 6;
    ws[P1_OFF + i] = W1[(u4 * 4 + du) * 16 + h];
  }
  if (i < 512) {
    int du = i & 3, h = (i >> 2) & 15, u4 = i >> 6;
    ws[P2_OFF + i] = W2[(u4 * 4 + du) * 16 + h];
  }
  if (i < 96) {
    int cidx = i >> 4, h = i & 15;
    float v;
    switch (cidx) {
      case 0:  v = wp0[0] * bg2[h];        break;
      case 1:  v = wp0[1] * bg2[32 + h];   break;
      case 2:  v = wp0[2] * bg2[96 + h];   break;
      case 3:  v = wp2[0] * bg2[16 + h] + wp2[2] * bg2[80 + h]; break;
      case 4:  v = wp2[1] * bg2[64 + h];   break;
      default: v = wp2[3] * bg2[128 + h];  break;
    }
    ws[CB_OFF + i] = v;
  }
  if (i < 64) ws[BG1_OFF + i] = bg1[i];
}

__global__ __launch_bounds__(TPB, 1) void node_kernel(
    const float* __restrict__ xsc, const float* __restrict__ xsp,
    const int* __restrict__ bidx, float* __restrict__ ws)
{
  __shared__ float accL[SPAN * 6];
  const int tid   = threadIdx.x;
  const int nl    = tid >> 1;         // node-local 0..63
  const int half  = tid & 1;          // output-half owned by this lane
  const int node  = blockIdx.x * NPB + nl;
  const int jbase = half * 32;        // gate j-half
  const int hoff  = half * 8;         // h-half as float4-row offset

  for (int i = tid; i < SPAN * 6; i += TPB) accL[i] = 0.f;
  __syncthreads();

  const float SQ2 = 1.41421356237f;
  const float I2  = 0.70710678118f;
  const float I6  = 0.40824829046f;

  // ---------- gate1 (j-split): hid_own[32] = silu((x @ Wg1 + bg1)[jbase..]) ----------
  float hid[32];
#pragma unroll
  for (int j = 0; j < 32; ++j) hid[j] = 0.f;
  {
    const float4* __restrict__ xp = (const float4*)(xsc + (size_t)node * 128);
    const float4* __restrict__ wg = (const float4*)(ws + PG1_OFF);
    for (int u4 = 0; u4 < 32; ++u4) {
      float4 x4 = xp[u4];
      const float4* __restrict__ wrow = wg + (u4 << 6) + jbase;
#pragma unroll
      for (int j = 0; j < 32; ++j) {
        float4 w = wrow[j];
        hid[j] = fmaf(x4.x, w.x, fmaf(x4.y, w.y, fmaf(x4.z, w.z, fmaf(x4.w, w.w, hid[j]))));
      }
    }
    const float* __restrict__ BG1 = ws + BG1_OFF;
#pragma unroll
    for (int j = 0; j < 32; ++j) {
      float hh = hid[j] + BG1[jbase + j];
      hid[j] = hh / (1.f + __expf(-hh));   // silu
    }
  }

  // ---------- coef (h-split): lane owns h = hoff*..  of all 6 groups ----------
  float c0[8], c1[8], c2[8], c3[8], c4[8], c5[8];
  {
    const float4* __restrict__ cbb = ((const float4*)(ws + CB_OFF)) + half * 2;
    float4 b;
    b = cbb[0];  c0[0]=b.x; c0[1]=b.y; c0[2]=b.z; c0[3]=b.w;
    b = cbb[1];  c0[4]=b.x; c0[5]=b.y; c0[6]=b.z; c0[7]=b.w;
    b = cbb[4];  c1[0]=b.x; c1[1]=b.y; c1[2]=b.z; c1[3]=b.w;
    b = cbb[5];  c1[4]=b.x; c1[5]=b.y; c1[6]=b.z; c1[7]=b.w;
    b = cbb[8];  c2[0]=b.x; c2[1]=b.y; c2[2]=b.z; c2[3]=b.w;
    b = cbb[9];  c2[4]=b.x; c2[5]=b.y; c2[6]=b.z; c2[7]=b.w;
    b = cbb[12]; c3[0]=b.x; c3[1]=b.y; c3[2]=b.z; c3[3]=b.w;
    b = cbb[13]; c3[4]=b.x; c3[5]=b.y; c3[6]=b.z; c3[7]=b.w;
    b = cbb[16]; c4[0]=b.x; c4[1]=b.y; c4[2]=b.z; c4[3]=b.w;
    b = cbb[17]; c4[4]=b.x; c4[5]=b.y; c4[6]=b.z; c4[7]=b.w;
    b = cbb[20]; c5[0]=b.x; c5[1]=b.y; c5[2]=b.z; c5[3]=b.w;
    b = cbb[21]; c5[4]=b.x; c5[5]=b.y; c5[6]=b.z; c5[7]=b.w;

    const float4* __restrict__ pcb = ((const float4*)(ws + PC_OFF)) + half * 2;
    auto acc_j = [&](int j, float hj) {
      const float4* __restrict__ row = pcb + j * 24;
      float4 w;
      w = row[0];  c0[0]=fmaf(hj,w.x,c0[0]); c0[1]=fmaf(hj,w.y,c0[1]); c0[2]=fmaf(hj,w.z,c0[2]); c0[3]=fmaf(hj,w.w,c0[3]);
      w = row[1];  c0[4]=fmaf(hj,w.x,c0[4]); c0[5]=fmaf(hj,w.y,c0[5]); c0[6]=fmaf(hj,w.z,c0[6]); c0[7]=fmaf(hj,w.w,c0[7]);
      w = row[4];  c1[0]=fmaf(hj,w.x,c1[0]); c1[1]=fmaf(hj,w.y,c1[1]); c1[2]=fmaf(hj,w.z,c1[2]); c1[3]=fmaf(hj,w.w,c1[3]);
      w = row[5];  c1[4]=fmaf(hj,w.x,c1[4]); c1[5]=fmaf(hj,w.y,c1[5]); c1[6]=fmaf(hj,w.z,c1[6]); c1[7]=fmaf(hj,w.w,c1[7]);
      w = row[8];  c2[0]=fmaf(hj,w.x,c2[0]); c2[1]=fmaf(hj,w.y,c2[1]); c2[2]=fmaf(hj,w.z,c2[2]); c2[3]=fmaf(hj,w.w,c2[3]);
      w = row[9];  c2[4]=fmaf(hj,w.x,c2[4]); c2[5]=fmaf(hj,w.y,c2[5]); c2[6]=fmaf(hj,w.z,c2[6]); c2[7]=fmaf(hj,w.w,c2[7]);
      w = row[12]; c3[0]=fmaf(hj,w.x,c3[0]); c3[1]=fmaf(hj,w.y,c3[1]); c3[2]=fmaf(hj,w.z,c3[2]); c3[3]=fmaf(hj,w.w,c3[3]);
      w = row[13]; c3[4]=fmaf(hj,w.x,c3[4]); c3[5]=fmaf(hj,w.y,c3[5]); c3[6]=fmaf(hj,w.z,c3[6]); c3[7]=fmaf(hj,w.w,c3[7]);
      w = row[16]; c4[0]=fmaf(hj,w.x,c4[0]); c4[1]=fmaf(hj,w.y,c4[1]); c4[2]=fmaf(hj,w.z,c4[2]); c4[3]=fmaf(hj,w.w,c4[3]);
      w = row[17]; c4[4]=fmaf(hj,w.x,c4[4]); c4[5]=fmaf(hj,w.y,c4[5]); c4[6]=fmaf(hj,w.z,c4[6]); c4[7]=fmaf(hj,w.w,c4[7]);
      w = row[20]; c5[0]=fmaf(hj,w.x,c5[0]); c5[1]=fmaf(hj,w.y,c5[1]); c5[2]=fmaf(hj,w.z,c5[2]); c5[3]=fmaf(hj,w.w,c5[3]);
      w = row[21]; c5[4]=fmaf(hj,w.x,c5[4]); c5[5]=fmaf(hj,w.y,c5[5]); c5[6]=fmaf(hj,w.z,c5[6]); c5[7]=fmaf(hj,w.w,c5[7]);
    };
    // pass 1: this lane's own j-half (hid[jj] = hid_{jbase+jj})
#pragma unroll 4
    for (int jj = 0; jj < 32; ++jj) acc_j(jbase + jj, hid[jj]);
    // exchange halves within the pair, then pass 2
#pragma unroll
    for (int jj = 0; jj < 32; ++jj) hid[jj] = __shfl_xor(hid[jj], 1);
    const int jb2 = 32 - jbase;
#pragma unroll 4
    for (int jj = 0; jj < 32; ++jj) acc_j(jb2 + jj, hid[jj]);
  }

  float o0 = 0.f;
  float o2m0 = 0.f, o2m1 = 0.f, o2m2 = 0.f, o2m3 = 0.f, o2m4 = 0.f;

  // ---------- s-phase (h-split) ----------
  {
    float s8[8];
#pragma unroll
    for (int i = 0; i < 8; ++i) s8[i] = 0.f;
    const float4* __restrict__ xp = (const float4*)(xsp + (size_t)node * 480);
    const float4* __restrict__ p0 = ((const float4*)(ws + P0_OFF)) + hoff;
    for (int u4 = 0; u4 < 32; ++u4) {
      float4 x4 = xp[u4];
      const float4* __restrict__ row = p0 + (u4 << 4);
#pragma unroll
      for (int i = 0; i < 8; ++i) {
        float4 w = row[i];
        s8[i] = fmaf(x4.x, w.x, fmaf(x4.y, w.y, fmaf(x4.z, w.z, fmaf(x4.w, w.w, s8[i]))));
      }
    }
#pragma unroll
    for (int i = 0; i < 8; ++i) {
      o0 = fmaf(c0[i] * s8[i], s8[i], o0);   // c0*s^2
      c3[i] *= s8[i];                        // c3 -> c3*s
    }
  }

  // ---------- v-phase (h-split) ----------
  {
    float v0[8], v1[8], v2[8];
#pragma unroll
    for (int i = 0; i < 8; ++i) { v0[i] = 0.f; v1[i] = 0.f; v2[i] = 0.f; }
    const float4* __restrict__ xp = (const float4*)(xsp + (size_t)node * 480 + 128);
    const float4* __restrict__ p1 = ((const float4*)(ws + P1_OFF)) + hoff;
    for (int u4 = 0; u4 < 16; ++u4) {
      float4 A = xp[3*u4], B = xp[3*u4+1], C = xp[3*u4+2];
      const float4* __restrict__ row = p1 + (u4 << 4);
#pragma unroll
      for (int i = 0; i < 8; ++i) {
        float4 w = row[i];
        v0[i] = fmaf(A.x, w.x, v0[i]); v1[i] = fmaf(A.y, w.x, v1[i]); v2[i] = fmaf(A.z, w.x, v2[i]);
        v0[i] = fmaf(A.w, w.y, v0[i]); v1[i] = fmaf(B.x, w.y, v1[i]); v2[i] = fmaf(B.y, w.y, v2[i]);
        v0[i] = fmaf(B.z, w.z, v0[i]); v1[i] = fmaf(B.w, w.z, v1[i]); v2[i] = fmaf(C.x, w.z, v2[i]);
        v0[i] = fmaf(C.y, w.w, v0[i]); v1[i] = fmaf(C.z, w.w, v1[i]); v2[i] = fmaf(C.w, w.w, v2[i]);
      }
    }
#pragma unroll
    for (int i = 0; i < 8; ++i) {
      float a = v0[i], b = v1[i], d = v2[i];
      float nv = fmaf(a, a, fmaf(b, b, d * d));
      o0 = fmaf(c1[i], nv, o0);                            // c1*|v|^2
      float c4h = c4[i];
      o2m0 = fmaf(c4h, SQ2 * d * a, o2m0);                 // vv5[0]
      o2m1 = fmaf(c4h, SQ2 * a * b, o2m1);                 // vv5[1]
      o2m2 = fmaf(c4h, (2.f*b*b - d*d - a*a) * I6, o2m2);  // vv5[2]
      o2m3 = fmaf(c4h, SQ2 * b * d, o2m3);                 // vv5[3]
      o2m4 = fmaf(c4h, (d*d - a*a) * I2, o2m4);            // vv5[4]
    }
  }

  // ---------- t-phase (h-split) ----------
  {
    float t0[8], t1[8], t2[8], t3[8], t4[8];
#pragma unroll
    for (int i = 0; i < 8; ++i) { t0[i]=0.f; t1[i]=0.f; t2[i]=0.f; t3[i]=0.f; t4[i]=0.f; }
    const float4* __restrict__ xp = (const float4*)(xsp + (size_t)node * 480 + 320);
    const float4* __restrict__ p2 = ((const float4*)(ws + P2_OFF)) + hoff;
    for (int u4 = 0; u4 < 8; ++u4) {
      float4 A = xp[5*u4], B = xp[5*u4+1], C = xp[5*u4+2], D = xp[5*u4+3], E = xp[5*u4+4];
      const float4* __restrict__ row = p2 + (u4 << 4);
#pragma unroll
      for (int i = 0; i < 8; ++i) {
        float4 w = row[i];
        t0[i]=fmaf(A.x,w.x,t0[i]); t1[i]=fmaf(A.y,w.x,t1[i]); t2[i]=fmaf(A.z,w.x,t2[i]); t3[i]=fmaf(A.w,w.x,t3[i]); t4[i]=fmaf(B.x,w.x,t4[i]);
        t0[i]=fmaf(B.y,w.y,t0[i]); t1[i]=fmaf(B.z,w.y,t1[i]); t2[i]=fmaf(B.w,w.y,t2[i]); t3[i]=fmaf(C.x,w.y,t3[i]); t4[i]=fmaf(C.y,w.y,t4[i]);
        t0[i]=fmaf(C.z,w.z,t0[i]); t1[i]=fmaf(C.w,w.z,t1[i]); t2[i]=fmaf(D.x,w.z,t2[i]); t3[i]=fmaf(D.y,w.z,t3[i]); t4[i]=fmaf(D.z,w.z,t4[i]);
        t0[i]=fmaf(D.w,w.w,t0[i]); t1[i]=fmaf(E.x,w.w,t1[i]); t2[i]=fmaf(E.y,w.w,t2[i]); t3[i]=fmaf(E.z,w.w,t3[i]); t4[i]=fmaf(E.w,w.w,t4[i]);
      }
    }
#pragma unroll
    for (int i = 0; i < 8; ++i) {
      float q0=t0[i], q1=t1[i], q2=t2[i], q3=t3[i], q4=t4[i];
      float nt = fmaf(q0,q0, fmaf(q1,q1, fmaf(q2,q2, fmaf(q3,q3, q4*q4))));
      o0 = fmaf(c2[i], nt, o0);                            // c2*|t|^2
      float c3sh = c3[i];                                  // (c3*s)
      o2m0 = fmaf(c3sh, q0, o2m0);
      o2m1 = fmaf(c3sh, q1, o2m1);
      o2m2 = fmaf(c3sh, q2, o2m2);
      o2m3 = fmaf(c3sh, q3, o2m3);
      o2m4 = fmaf(c3sh, q4, o2m4);
      // T (symmetric traceless) from t5, A = T*T
      float d0 = -q2*I6 - q4*I2;
      float d1 =  2.f*q2*I6;
      float d2 = -q2*I6 + q4*I2;
      float a = q1*I2, b = q0*I2, cc = q3*I2;
      float A00 = fmaf(d0,d0, fmaf(a,a, b*b));
      float A11 = fmaf(a,a, fmaf(d1,d1, cc*cc));
      float A22 = fmaf(b,b, fmaf(cc,cc, d2*d2));
      float A01 = fmaf(a, d0 + d1, b*cc);
      float A02 = fmaf(b, d0 + d2, a*cc);
      float A12 = fmaf(cc, d1 + d2, a*b);
      float c5h = c5[i];
      o2m0 = fmaf(c5h, SQ2 * A02, o2m0);
      o2m1 = fmaf(c5h, SQ2 * A01, o2m1);
      o2m2 = fmaf(c5h, (2.f*A11 - A22 - A00) * I6, o2m2);
      o2m3 = fmaf(c5h, SQ2 * A12, o2m3);
      o2m4 = fmaf(c5h, (A22 - A00) * I2, o2m4);
    }
  }

  // ---------- combine lane pair, then segment accumulate ----------
  o0   += __shfl_xor(o0,   1);
  o2m0 += __shfl_xor(o2m0, 1);
  o2m1 += __shfl_xor(o2m1, 1);
  o2m2 += __shfl_xor(o2m2, 1);
  o2m3 += __shfl_xor(o2m3, 1);
  o2m4 += __shfl_xor(o2m4, 1);

  int g = bidx[node];
  int gmin = bidx[blockIdx.x * NPB];
  int rel = g - gmin;
  float* __restrict__ ACC = ws + ACC_OFF;
  if (half == 0) {
    if (rel < SPAN) {
      atomicAdd(&accL[rel*6 + 0], o0);
      atomicAdd(&accL[rel*6 + 1], o2m0);
      atomicAdd(&accL[rel*6 + 2], o2m1);
      atomicAdd(&accL[rel*6 + 3], o2m2);
      atomicAdd(&accL[rel*6 + 4], o2m3);
      atomicAdd(&accL[rel*6 + 5], o2m4);
    } else {
      atomicAdd(&ACC[g*6 + 0], o0);
      atomicAdd(&ACC[g*6 + 1], o2m0);
      atomicAdd(&ACC[g*6 + 2], o2m1);
      atomicAdd(&ACC[g*6 + 3], o2m2);
      atomicAdd(&ACC[g*6 + 4], o2m3);
      atomicAdd(&ACC[g*6 + 5], o2m4);
    }
  }
  __syncthreads();
  for (int i = tid; i < SPAN * 6; i += TPB) {
    float val = accL[i];
    if (val != 0.f) atomicAdd(&ACC[(gmin + i / 6) * 6 + (i % 6)], val);
  }
}

__global__ __launch_bounds__(64) void finalize_kernel(
    const float* __restrict__ ws, float* __restrict__ out)
{
  int g = blockIdx.x * 64 + threadIdx.x;
  if (g >= G_GRP) return;
  const float I2 = 0.70710678118f, I3 = 0.57735026919f, I6 = 0.40824829046f;
  const float* A = ws + ACC_OFF + g * 6;
  float g0 = A[0], q0 = A[1], q1 = A[2], q2 = A[3], q3 = A[4], q4 = A[5];
  float M00 = g0*I3 - q2*I6 - q4*I2;
  float M11 = g0*I3 + 2.f*q2*I6;
  float M22 = g0*I3 - q2*I6 + q4*I2;
  float M01 = q1*I2, M02 = q0*I2, M12 = q3*I2;
  float* o = out + g * 9;
  // out[a][b] = M[p[a]][p[b]], p = {2,0,1}
  o[0] = M22; o[1] = M02; o[2] = M12;
  o[3] = M02; o[4] = M00; o[5] = M01;
  o[6] = M12; o[7] = M01; o[8] = M11;
}

extern "C" void kernel_launch(void* const* d_in, const int* in_sizes, int n_in,
                              void* d_out, int out_size, void* d_ws, size_t ws_size,
                              hipStream_t stream)
{
  const float* xsc = (const float*)d_in[0];   // x_scalar  (N,128)
  const float* xsp = (const float*)d_in[1];   // x_spherical (N,480)
  // d_in[2] = coord (unused)
  const int*   bidx = (const int*)d_in[3];    // batch_index (N,)
  const float* W0  = (const float*)d_in[4];
  const float* W1  = (const float*)d_in[5];
  const float* W2  = (const float*)d_in[6];
  const float* Wg1 = (const float*)d_in[7];
  const float* bg1 = (const float*)d_in[8];
  const float* Wg2 = (const float*)d_in[9];
  const float* bg2 = (const float*)d_in[10];
  const float* wp0 = (const float*)d_in[11];
  const float* wp2 = (const float*)d_in[12];
  float* ws = (float*)d_ws;

  hipMemsetAsync(d_ws, 0, 3072 * sizeof(float), stream);
  repack_kernel<<<32, 256, 0, stream>>>(W0, W1, W2, Wg1, bg1, Wg2, bg2, wp0, wp2, ws);
  node_kernel<<<N_NODES / NPB, TPB, 0, stream>>>(xsc, xsp, bidx, ws);
  finalize_kernel<<<(G_GRP + 63) / 64, 64, 0, stream>>>(ws, (float*)d_out);
}

// Round 10
// 102.701 us; speedup vs baseline: 8.5722x; 5.3131x over previous
//
#include <hip/hip_runtime.h>
#include <math.h>

#define N_NODES 131072
#define G_GRP   512
#define TPB     256          // 4 waves; wave handles 16 nodes
#define NPB     64           // nodes per block
#define SPAN    32

// ws float offsets
#define ACC_OFF    0         // 3072 floats (512 groups * 6)
#define WB_OFF_F   4096      // 38400 ushort (bf16 weight frags) = 19200 floats
#define CB_OFF_F   23552     // 96 floats (bg2*wpost combos)
#define BG1_OFF_F  23680     // 64 floats

// frag index bases (each frag = 64 lanes x 8 bf16 = 512 ushort)
#define FG1 0    // gate : 16 frags, t*4+kk   (K=128, Ntiles=4)
#define FG2 16   // coef : 12 frags, g*2+kk   (K=64,  Ntiles=6)
#define FG3 28   // s    : 4  frags, kk       (K=128, Ntiles=1)
#define FG4 32   // v    : 18 frags, i*6+kk   (K=192 blockdiag, Ntiles=3)
#define FG5 50   // t    : 25 frags, m*5+kk   (K=160 blockdiag, Ntiles=5)

typedef __attribute__((ext_vector_type(8))) short short8;
typedef __attribute__((ext_vector_type(4))) float f32x4;

__device__ __forceinline__ unsigned short f2bf(float f) {
  union { float f; unsigned u; } v; v.f = f;
  unsigned r = v.u + 0x7FFFu + ((v.u >> 16) & 1u);   // RNE
  return (unsigned short)(r >> 16);
}

__global__ __launch_bounds__(256) void repack_kernel(
    const float* __restrict__ W0, const float* __restrict__ W1,
    const float* __restrict__ W2, const float* __restrict__ Wg1,
    const float* __restrict__ bg1, const float* __restrict__ Wg2,
    const float* __restrict__ bg2, const float* __restrict__ wp0,
    const float* __restrict__ wp2, float* __restrict__ ws)
{
  int i = blockIdx.x * 256 + threadIdx.x;
  unsigned short* WB = (unsigned short*)(ws + WB_OFF_F);
  if (i < 38400) {
    int fidx = i >> 9;
    int le = i & 511, l = le >> 3, j = le & 7;
    int lo = l & 15, hi = l >> 4;
    float val = 0.f;
    if (fidx < 16) {                       // gate: B[k][t*16+lo] = Wg1[k][col]
      int t = fidx >> 2, kk = fidx & 3;
      int k = kk * 32 + hi * 8 + j;
      val = Wg1[k * 64 + t * 16 + lo];
    } else if (fidx < 28) {                // coef: wpost-folded Wg2
      int f = fidx - 16, g = f >> 1, kk = f & 1;
      int k = kk * 32 + hi * 8 + j;
      const float* row = Wg2 + k * 144;
      int h = lo;
      switch (g) {
        case 0:  val = wp0[0] * row[h];        break;
        case 1:  val = wp0[1] * row[32 + h];   break;
        case 2:  val = wp0[2] * row[96 + h];   break;
        case 3:  val = wp2[0] * row[16 + h] + wp2[2] * row[80 + h]; break;
        case 4:  val = wp2[1] * row[64 + h];   break;
        default: val = wp2[3] * row[128 + h];  break;
      }
    } else if (fidx < 32) {                // s: W0[k][lo]
      int kk = fidx - 28;
      int k = kk * 32 + hi * 8 + j;
      val = W0[k * 16 + lo];
    } else if (fidx < 50) {                // v blockdiag: k=u*3+ic, col=i*16+h
      int f = fidx - 32, ic = f / 6, kk = f % 6;
      int k = kk * 32 + hi * 8 + j;
      int u = k / 3, cc = k - u * 3;
      val = (cc == ic) ? W1[u * 16 + lo] : 0.f;
    } else {                               // t blockdiag: k=u*5+mc, col=m*16+h
      int f = fidx - 50, mt = f / 5, kk = f % 5;
      int k = kk * 32 + hi * 8 + j;
      int u = k / 5, mc = k - u * 5;
      val = (mc == mt) ? W2[u * 16 + lo] : 0.f;
    }
    WB[i] = f2bf(val);
  } else if (i < 38496) {                  // CB (fp32)
    int o = i - 38400, g = o >> 4, h = o & 15;
    float v;
    switch (g) {
      case 0:  v = wp0[0] * bg2[h];        break;
      case 1:  v = wp0[1] * bg2[32 + h];   break;
      case 2:  v = wp0[2] * bg2[96 + h];   break;
      case 3:  v = wp2[0] * bg2[16 + h] + wp2[2] * bg2[80 + h]; break;
      case 4:  v = wp2[1] * bg2[64 + h];   break;
      default: v = wp2[3] * bg2[128 + h];  break;
    }
    ws[CB_OFF_F + o] = v;
  } else if (i < 38560) {
    ws[BG1_OFF_F + (i - 38496)] = bg1[i - 38496];
  }
}

__global__ __launch_bounds__(TPB, 1) void node_kernel(
    const float* __restrict__ xsc, const float* __restrict__ xsp,
    const int* __restrict__ bidx, float* __restrict__ ws)
{
  __shared__ unsigned short XS[64 * 200];      // padded x tile (reused per phase)
  __shared__ unsigned short HB[4 * 16 * 72];   // per-wave silu(H) bf16, stride 72
  __shared__ float accL[SPAN * 6];
  const int tid = threadIdx.x;
  const int w = tid >> 6, l = tid & 63;
  const int lo = l & 15, hi = l >> 4;
  const int blk = blockIdx.x;
  const unsigned short* __restrict__ WB = (const unsigned short*)(ws + WB_OFF_F);

  for (int i = tid; i < SPAN * 6; i += TPB) accL[i] = 0.f;

  const float SQ2 = 1.41421356237f;
  const float I2  = 0.70710678118f;
  const float I6  = 0.40824829046f;

  // coalesced fp32->bf16 stage of a [64 x K] tile into XS (row stride ldsStride)
  auto stage = [&](const float* __restrict__ src, int srcStride, int K, int ldsStride) {
    int f4n = K >> 2;
    int total = 64 * f4n;
    for (int idx = tid; idx < total; idx += TPB) {
      int row = idx / f4n, c4 = idx - row * f4n;
      float4 v = *(const float4*)(src + (size_t)(blk * 64 + row) * srcStride + c4 * 4);
      uint2 pk;
      pk.x = (unsigned)f2bf(v.x) | ((unsigned)f2bf(v.y) << 16);
      pk.y = (unsigned)f2bf(v.z) | ((unsigned)f2bf(v.w) << 16);
      *(uint2*)(&XS[row * ldsStride + c4 * 4]) = pk;
    }
  };
  auto afrag = [&](int kk, int ldsStride) -> short8 {
    return *(const short8*)(&XS[(w * 16 + lo) * ldsStride + kk * 32 + hi * 8]);
  };
  auto bfrag = [&](int fidx) -> short8 {
    return *(const short8*)(WB + (fidx << 9) + (l << 3));
  };

  __syncthreads();
  stage(xsc, 128, 128, 136);
  __syncthreads();

  // ---------- G1: gate H[16x64] ----------
  f32x4 hacc[4];
  {
    short8 a0 = afrag(0,136), a1 = afrag(1,136), a2 = afrag(2,136), a3 = afrag(3,136);
#pragma unroll
    for (int t = 0; t < 4; ++t) {
      f32x4 acc = {0.f, 0.f, 0.f, 0.f};
      acc = __builtin_amdgcn_mfma_f32_16x16x32_bf16(a0, bfrag(FG1 + t*4 + 0), acc, 0, 0, 0);
      acc = __builtin_amdgcn_mfma_f32_16x16x32_bf16(a1, bfrag(FG1 + t*4 + 1), acc, 0, 0, 0);
      acc = __builtin_amdgcn_mfma_f32_16x16x32_bf16(a2, bfrag(FG1 + t*4 + 2), acc, 0, 0, 0);
      acc = __builtin_amdgcn_mfma_f32_16x16x32_bf16(a3, bfrag(FG1 + t*4 + 3), acc, 0, 0, 0);
      hacc[t] = acc;
    }
  }
  // silu + bias -> HB (bf16), C-layout row = hi*4+r, col = t*16+lo
  {
    const float* __restrict__ BG1f = ws + BG1_OFF_F;
    unsigned short* __restrict__ hb = &HB[w * 16 * 72];
#pragma unroll
    for (int t = 0; t < 4; ++t) {
      float bb = BG1f[t * 16 + lo];
#pragma unroll
      for (int r = 0; r < 4; ++r) {
        float hv = hacc[t][r] + bb;
        float sg = hv / (1.f + __expf(-hv));
        hb[(hi * 4 + r) * 72 + t * 16 + lo] = f2bf(sg);
      }
    }
  }
  // ---------- G2: coef C[16x96] (A from HB, same wave -> no barrier) ----------
  f32x4 cacc[6];
  {
    const unsigned short* __restrict__ hb = &HB[w * 16 * 72];
    short8 a0 = *(const short8*)(&hb[lo * 72 + hi * 8]);
    short8 a1 = *(const short8*)(&hb[lo * 72 + 32 + hi * 8]);
#pragma unroll
    for (int g = 0; g < 6; ++g) {
      f32x4 acc = {0.f, 0.f, 0.f, 0.f};
      acc = __builtin_amdgcn_mfma_f32_16x16x32_bf16(a0, bfrag(FG2 + g*2 + 0), acc, 0, 0, 0);
      acc = __builtin_amdgcn_mfma_f32_16x16x32_bf16(a1, bfrag(FG2 + g*2 + 1), acc, 0, 0, 0);
      float cb = ws[CB_OFF_F + g * 16 + lo];
      acc[0] += cb; acc[1] += cb; acc[2] += cb; acc[3] += cb;
      cacc[g] = acc;
    }
  }

  __syncthreads();
  stage(xsp, 480, 128, 136);
  __syncthreads();

  // ---------- G3: s[16x16] ----------
  f32x4 sacc = {0.f, 0.f, 0.f, 0.f};
  {
    short8 a0 = afrag(0,136), a1 = afrag(1,136), a2 = afrag(2,136), a3 = afrag(3,136);
    sacc = __builtin_amdgcn_mfma_f32_16x16x32_bf16(a0, bfrag(FG3 + 0), sacc, 0, 0, 0);
    sacc = __builtin_amdgcn_mfma_f32_16x16x32_bf16(a1, bfrag(FG3 + 1), sacc, 0, 0, 0);
    sacc = __builtin_amdgcn_mfma_f32_16x16x32_bf16(a2, bfrag(FG3 + 2), sacc, 0, 0, 0);
    sacc = __builtin_amdgcn_mfma_f32_16x16x32_bf16(a3, bfrag(FG3 + 3), sacc, 0, 0, 0);
  }
  f32x4 P0 = {0,0,0,0}, Q0 = {0,0,0,0}, Q1 = {0,0,0,0},
        Q2 = {0,0,0,0}, Q3 = {0,0,0,0}, Q4 = {0,0,0,0};
#pragma unroll
  for (int r = 0; r < 4; ++r) {
    float s = sacc[r];
    P0[r] = fmaf(cacc[0][r] * s, s, P0[r]);   // c0*s^2
    cacc[3][r] *= s;                          // c3 -> c3*s
  }

  __syncthreads();
  stage(xsp + 128, 480, 192, 200);
  __syncthreads();

  // ---------- G4: v[16x48] (3 tiles = components i) ----------
  f32x4 vacc[3];
  {
    short8 a[6];
#pragma unroll
    for (int kk = 0; kk < 6; ++kk) a[kk] = afrag(kk, 200);
#pragma unroll
    for (int i = 0; i < 3; ++i) {
      f32x4 acc = {0.f, 0.f, 0.f, 0.f};
#pragma unroll
      for (int kk = 0; kk < 6; ++kk)
        acc = __builtin_amdgcn_mfma_f32_16x16x32_bf16(a[kk], bfrag(FG4 + i*6 + kk), acc, 0, 0, 0);
      vacc[i] = acc;
    }
  }
#pragma unroll
  for (int r = 0; r < 4; ++r) {
    float a = vacc[0][r], b = vacc[1][r], d = vacc[2][r];
    float nv = fmaf(a, a, fmaf(b, b, d * d));
    P0[r] = fmaf(cacc[1][r], nv, P0[r]);                     // c1*|v|^2
    float c4h = cacc[4][r];
    Q0[r] = fmaf(c4h, SQ2 * d * a, Q0[r]);
    Q1[r] = fmaf(c4h, SQ2 * a * b, Q1[r]);
    Q2[r] = fmaf(c4h, (2.f*b*b - d*d - a*a) * I6, Q2[r]);
    Q3[r] = fmaf(c4h, SQ2 * b * d, Q3[r]);
    Q4[r] = fmaf(c4h, (d*d - a*a) * I2, Q4[r]);
  }

  __syncthreads();
  stage(xsp + 320, 480, 160, 168);
  __syncthreads();

  // ---------- G5: t5[16x80] (5 tiles = components m) ----------
  f32x4 tacc[5];
  {
    short8 a[5];
#pragma unroll
    for (int kk = 0; kk < 5; ++kk) a[kk] = afrag(kk, 168);
#pragma unroll
    for (int m = 0; m < 5; ++m) {
      f32x4 acc = {0.f, 0.f, 0.f, 0.f};
#pragma unroll
      for (int kk = 0; kk < 5; ++kk)
        acc = __builtin_amdgcn_mfma_f32_16x16x32_bf16(a[kk], bfrag(FG5 + m*5 + kk), acc, 0, 0, 0);
      tacc[m] = acc;
    }
  }
#pragma unroll
  for (int r = 0; r < 4; ++r) {
    float q0 = tacc[0][r], q1 = tacc[1][r], q2 = tacc[2][r], q3 = tacc[3][r], q4 = tacc[4][r];
    float nt = fmaf(q0,q0, fmaf(q1,q1, fmaf(q2,q2, fmaf(q3,q3, q4*q4))));
    P0[r] = fmaf(cacc[2][r], nt, P0[r]);                     // c2*|t|^2
    float c3s = cacc[3][r];
    Q0[r] = fmaf(c3s, q0, Q0[r]);
    Q1[r] = fmaf(c3s, q1, Q1[r]);
    Q2[r] = fmaf(c3s, q2, Q2[r]);
    Q3[r] = fmaf(c3s, q3, Q3[r]);
    Q4[r] = fmaf(c3s, q4, Q4[r]);
    float d0 = -q2*I6 - q4*I2;
    float d1 =  2.f*q2*I6;
    float d2 = -q2*I6 + q4*I2;
    float a = q1*I2, b = q0*I2, cc = q3*I2;
    float A00 = fmaf(d0,d0, fmaf(a,a, b*b));
    float A11 = fmaf(a,a, fmaf(d1,d1, cc*cc));
    float A22 = fmaf(b,b, fmaf(cc,cc, d2*d2));
    float A01 = fmaf(a, d0 + d1, b*cc);
    float A02 = fmaf(b, d0 + d2, a*cc);
    float A12 = fmaf(cc, d1 + d2, a*b);
    float c5h = cacc[5][r];
    Q0[r] = fmaf(c5h, SQ2 * A02, Q0[r]);
    Q1[r] = fmaf(c5h, SQ2 * A01, Q1[r]);
    Q2[r] = fmaf(c5h, (2.f*A11 - A22 - A00) * I6, Q2[r]);
    Q3[r] = fmaf(c5h, SQ2 * A12, Q3[r]);
    Q4[r] = fmaf(c5h, (A22 - A00) * I2, Q4[r]);
  }

  // ---------- reduce over 16 h-lanes, segment accumulate ----------
  float* __restrict__ ACC = ws + ACC_OFF;
  int gmin = bidx[blk * 64];
#pragma unroll
  for (int r = 0; r < 4; ++r) {
    float z0 = P0[r], z1 = Q0[r], z2 = Q1[r], z3 = Q2[r], z4 = Q3[r], z5 = Q4[r];
#pragma unroll
    for (int d = 1; d < 16; d <<= 1) {
      z0 += __shfl_xor(z0, d); z1 += __shfl_xor(z1, d); z2 += __shfl_xor(z2, d);
      z3 += __shfl_xor(z3, d); z4 += __shfl_xor(z4, d); z5 += __shfl_xor(z5, d);
    }
    if (lo == 0) {
      int node = blk * 64 + w * 16 + hi * 4 + r;
      int g = bidx[node];
      int rel = g - gmin;
      if (rel < SPAN) {
        atomicAdd(&accL[rel*6 + 0], z0); atomicAdd(&accL[rel*6 + 1], z1);
        atomicAdd(&accL[rel*6 + 2], z2); atomicAdd(&accL[rel*6 + 3], z3);
        atomicAdd(&accL[rel*6 + 4], z4); atomicAdd(&accL[rel*6 + 5], z5);
      } else {
        atomicAdd(&ACC[g*6 + 0], z0); atomicAdd(&ACC[g*6 + 1], z1);
        atomicAdd(&ACC[g*6 + 2], z2); atomicAdd(&ACC[g*6 + 3], z3);
        atomicAdd(&ACC[g*6 + 4], z4); atomicAdd(&ACC[g*6 + 5], z5);
      }
    }
  }
  __syncthreads();
  for (int i = tid; i < SPAN * 6; i += TPB) {
    float val = accL[i];
    if (val != 0.f) atomicAdd(&ACC[gmin * 6 + i], val);
  }
}

__global__ __launch_bounds__(64) void finalize_kernel(
    const float* __restrict__ ws, float* __restrict__ out)
{
  int g = blockIdx.x * 64 + threadIdx.x;
  if (g >= G_GRP) return;
  const float I2 = 0.70710678118f, I3 = 0.57735026919f, I6 = 0.40824829046f;
  const float* A = ws + ACC_OFF + g * 6;
  float g0 = A[0], q0 = A[1], q1 = A[2], q2 = A[3], q3 = A[4], q4 = A[5];
  float M00 = g0*I3 - q2*I6 - q4*I2;
  float M11 = g0*I3 + 2.f*q2*I6;
  float M22 = g0*I3 - q2*I6 + q4*I2;
  float M01 = q1*I2, M02 = q0*I2, M12 = q3*I2;
  float* o = out + g * 9;
  o[0] = M22; o[1] = M02; o[2] = M12;
  o[3] = M02; o[4] = M00; o[5] = M01;
  o[6] = M12; o[7] = M01; o[8] = M11;
}

extern "C" void kernel_launch(void* const* d_in, const int* in_sizes, int n_in,
                              void* d_out, int out_size, void* d_ws, size_t ws_size,
                              hipStream_t stream)
{
  const float* xsc = (const float*)d_in[0];
  const float* xsp = (const float*)d_in[1];
  const int*   bidx = (const int*)d_in[3];
  const float* W0  = (const float*)d_in[4];
  const float* W1  = (const float*)d_in[5];
  const float* W2  = (const float*)d_in[6];
  const float* Wg1 = (const float*)d_in[7];
  const float* bg1 = (const float*)d_in[8];
  const float* Wg2 = (const float*)d_in[9];
  const float* bg2 = (const float*)d_in[10];
  const float* wp0 = (const float*)d_in[11];
  const float* wp2 = (const float*)d_in[12];
  float* ws = (float*)d_ws;

  hipMemsetAsync(d_ws, 0, 3072 * sizeof(float), stream);
  repack_kernel<<<151, 256, 0, stream>>>(W0, W1, W2, Wg1, bg1, Wg2, bg2, wp0, wp2, ws);
  node_kernel<<<N_NODES / NPB, TPB, 0, stream>>>(xsc, xsp, bidx, ws);
  finalize_kernel<<<(G_GRP + 63) / 64, 64, 0, stream>>>(ws, (float*)d_out);
}

// Round 11
// 79.878 us; speedup vs baseline: 11.0214x; 1.2857x over previous
//
#include <hip/hip_runtime.h>
#include <math.h>

#define N_NODES 131072
#define G_GRP   512
#define TPB     256          // 4 waves; wave handles 16 nodes
#define NPB     64           // nodes per block
#define SPAN    32

// ws float offsets
#define ACC_OFF    0         // 3072 floats (512 groups * 6)
#define WB_OFF_F   4096      // 38400 ushort (bf16 weight frags) = 19200 floats
#define CB_OFF_F   23552     // 96 floats (bg2*wpost combos)
#define BG1_OFF_F  23680     // 64 floats

// frag index bases (each frag = 64 lanes x 8 bf16 = 512 ushort)
#define FG1 0    // gate : 16 frags, t*4+kk   (K=128, Ntiles=4)
#define FG2 16   // coef : 12 frags, g*2+kk   (K=64,  Ntiles=6)
#define FG3 28   // s    : 4  frags, kk       (K=128, Ntiles=1)
#define FG4 32   // v    : 18 frags, i*6+kk   (K=192 blockdiag, Ntiles=3)
#define FG5 50   // t    : 25 frags, m*5+kk   (K=160 blockdiag, Ntiles=5)

typedef __attribute__((ext_vector_type(8))) short short8;
typedef __attribute__((ext_vector_type(4))) float f32x4;

__device__ __forceinline__ unsigned short f2bf(float f) {
  union { float f; unsigned u; } v; v.f = f;
  unsigned r = v.u + 0x7FFFu + ((v.u >> 16) & 1u);   // RNE
  return (unsigned short)(r >> 16);
}

__global__ __launch_bounds__(256) void repack_kernel(
    const float* __restrict__ W0, const float* __restrict__ W1,
    const float* __restrict__ W2, const float* __restrict__ Wg1,
    const float* __restrict__ bg1, const float* __restrict__ Wg2,
    const float* __restrict__ bg2, const float* __restrict__ wp0,
    const float* __restrict__ wp2, float* __restrict__ ws)
{
  int i = blockIdx.x * 256 + threadIdx.x;
  if (i < 3072) ws[ACC_OFF + i] = 0.f;               // zero group accumulator
  unsigned short* WB = (unsigned short*)(ws + WB_OFF_F);
  if (i < 38400) {
    int fidx = i >> 9;
    int le = i & 511, l = le >> 3, j = le & 7;
    int lo = l & 15, hi = l >> 4;
    float val = 0.f;
    if (fidx < 16) {                       // gate: B[k][t*16+lo] = Wg1[k][col]
      int t = fidx >> 2, kk = fidx & 3;
      int k = kk * 32 + hi * 8 + j;
      val = Wg1[k * 64 + t * 16 + lo];
    } else if (fidx < 28) {                // coef: wpost-folded Wg2
      int f = fidx - 16, g = f >> 1, kk = f & 1;
      int k = kk * 32 + hi * 8 + j;
      const float* row = Wg2 + k * 144;
      int h = lo;
      switch (g) {
        case 0:  val = wp0[0] * row[h];        break;
        case 1:  val = wp0[1] * row[32 + h];   break;
        case 2:  val = wp0[2] * row[96 + h];   break;
        case 3:  val = wp2[0] * row[16 + h] + wp2[2] * row[80 + h]; break;
        case 4:  val = wp2[1] * row[64 + h];   break;
        default: val = wp2[3] * row[128 + h];  break;
      }
    } else if (fidx < 32) {                // s: W0[k][lo]
      int kk = fidx - 28;
      int k = kk * 32 + hi * 8 + j;
      val = W0[k * 16 + lo];
    } else if (fidx < 50) {                // v blockdiag: k=u*3+ic, col=i*16+h
      int f = fidx - 32, ic = f / 6, kk = f % 6;
      int k = kk * 32 + hi * 8 + j;
      int u = k / 3, cc = k - u * 3;
      val = (cc == ic) ? W1[u * 16 + lo] : 0.f;
    } else {                               // t blockdiag: k=u*5+mc, col=m*16+h
      int f = fidx - 50, mt = f / 5, kk = f % 5;
      int k = kk * 32 + hi * 8 + j;
      int u = k / 5, mc = k - u * 5;
      val = (mc == mt) ? W2[u * 16 + lo] : 0.f;
    }
    WB[i] = f2bf(val);
  } else if (i < 38496) {                  // CB (fp32)
    int o = i - 38400, g = o >> 4, h = o & 15;
    float v;
    switch (g) {
      case 0:  v = wp0[0] * bg2[h];        break;
      case 1:  v = wp0[1] * bg2[32 + h];   break;
      case 2:  v = wp0[2] * bg2[96 + h];   break;
      case 3:  v = wp2[0] * bg2[16 + h] + wp2[2] * bg2[80 + h]; break;
      case 4:  v = wp2[1] * bg2[64 + h];   break;
      default: v = wp2[3] * bg2[128 + h];  break;
    }
    ws[CB_OFF_F + o] = v;
  } else if (i < 38560) {
    ws[BG1_OFF_F + (i - 38496)] = bg1[i - 38496];
  }
}

// ---- templated staging (compile-time F4N/stride: no runtime idiv) ----
template <int F4N>
__device__ __forceinline__ void ld_tile(const float* __restrict__ src, int srcStride,
                                        int baseRow, int tid, float4* __restrict__ buf)
{
#pragma unroll
  for (int it = 0; it < (64 * F4N) / TPB; ++it) {
    int idx = it * TPB + tid;
    int row = idx / F4N, c4 = idx - row * F4N;
    buf[it] = *(const float4*)(src + (size_t)(baseRow + row) * srcStride + c4 * 4);
  }
}
template <int F4N, int LDSS>
__device__ __forceinline__ void st_tile(unsigned short* __restrict__ XS, int tid,
                                        const float4* __restrict__ buf)
{
#pragma unroll
  for (int it = 0; it < (64 * F4N) / TPB; ++it) {
    int idx = it * TPB + tid;
    int row = idx / F4N, c4 = idx - row * F4N;
    uint2 pk;
    pk.x = (unsigned)f2bf(buf[it].x) | ((unsigned)f2bf(buf[it].y) << 16);
    pk.y = (unsigned)f2bf(buf[it].z) | ((unsigned)f2bf(buf[it].w) << 16);
    *(uint2*)(&XS[row * LDSS + c4 * 4]) = pk;
  }
}
template <int F4N, int LDSS>
__device__ __forceinline__ void stage_sync(const float* __restrict__ src, int srcStride,
                                           int baseRow, int tid,
                                           unsigned short* __restrict__ XS)
{
#pragma unroll 2
  for (int it = 0; it < (64 * F4N) / TPB; ++it) {
    int idx = it * TPB + tid;
    int row = idx / F4N, c4 = idx - row * F4N;
    float4 v = *(const float4*)(src + (size_t)(baseRow + row) * srcStride + c4 * 4);
    uint2 pk;
    pk.x = (unsigned)f2bf(v.x) | ((unsigned)f2bf(v.y) << 16);
    pk.y = (unsigned)f2bf(v.z) | ((unsigned)f2bf(v.w) << 16);
    *(uint2*)(&XS[row * LDSS + c4 * 4]) = pk;
  }
}

__global__ __launch_bounds__(TPB, 4) void node_kernel(
    const float* __restrict__ xsc, const float* __restrict__ xsp,
    const int* __restrict__ bidx, float* __restrict__ ws)
{
  __shared__ unsigned short XS[64 * 200];      // padded x tile (reused per phase)
  __shared__ unsigned short HB[4 * 16 * 72];   // per-wave silu(H) bf16, stride 72
  __shared__ float accL[SPAN * 6];
  const int tid = threadIdx.x;
  const int w = tid >> 6, l = tid & 63;
  const int lo = l & 15, hi = l >> 4;
  const int blk = blockIdx.x;
  const int baseRow = blk * 64;
  const unsigned short* __restrict__ WB = (const unsigned short*)(ws + WB_OFF_F);

  for (int i = tid; i < SPAN * 6; i += TPB) accL[i] = 0.f;

  const float SQ2 = 1.41421356237f;
  const float I2  = 0.70710678118f;
  const float I6  = 0.40824829046f;

  auto afrag = [&](int kk, int ldsStride) -> short8 {
    return *(const short8*)(&XS[(w * 16 + lo) * ldsStride + kk * 32 + hi * 8]);
  };
  auto bfrag = [&](int fidx) -> short8 {
    return *(const short8*)(WB + (fidx << 9) + (l << 3));
  };

  // stage gate tile (synchronous)
  stage_sync<32, 136>(xsc, 128, baseRow, tid, XS);
  __syncthreads();

  // prefetch s tile while G1/G2 compute (T14: issue-early / write-late)
  float4 bufS[8];
  ld_tile<32>(xsp, 480, baseRow, tid, bufS);

  // ---------- G1: gate H[16x64] ----------
  f32x4 hacc[4];
  {
    short8 a0 = afrag(0,136), a1 = afrag(1,136), a2 = afrag(2,136), a3 = afrag(3,136);
#pragma unroll
    for (int t = 0; t < 4; ++t) {
      f32x4 acc = {0.f, 0.f, 0.f, 0.f};
      acc = __builtin_amdgcn_mfma_f32_16x16x32_bf16(a0, bfrag(FG1 + t*4 + 0), acc, 0, 0, 0);
      acc = __builtin_amdgcn_mfma_f32_16x16x32_bf16(a1, bfrag(FG1 + t*4 + 1), acc, 0, 0, 0);
      acc = __builtin_amdgcn_mfma_f32_16x16x32_bf16(a2, bfrag(FG1 + t*4 + 2), acc, 0, 0, 0);
      acc = __builtin_amdgcn_mfma_f32_16x16x32_bf16(a3, bfrag(FG1 + t*4 + 3), acc, 0, 0, 0);
      hacc[t] = acc;
    }
  }
  // silu + bias -> HB (bf16), C-layout row = hi*4+r, col = t*16+lo
  {
    const float* __restrict__ BG1f = ws + BG1_OFF_F;
    unsigned short* __restrict__ hb = &HB[w * 16 * 72];
#pragma unroll
    for (int t = 0; t < 4; ++t) {
      float bb = BG1f[t * 16 + lo];
#pragma unroll
      for (int r = 0; r < 4; ++r) {
        float hv = hacc[t][r] + bb;
        float sg = hv / (1.f + __expf(-hv));
        hb[(hi * 4 + r) * 72 + t * 16 + lo] = f2bf(sg);
      }
    }
  }
  // ---------- G2: coef C[16x96] (A from HB, same wave -> no barrier) ----------
  f32x4 cacc[6];
  {
    const unsigned short* __restrict__ hb = &HB[w * 16 * 72];
    short8 a0 = *(const short8*)(&hb[lo * 72 + hi * 8]);
    short8 a1 = *(const short8*)(&hb[lo * 72 + 32 + hi * 8]);
#pragma unroll
    for (int g = 0; g < 6; ++g) {
      f32x4 acc = {0.f, 0.f, 0.f, 0.f};
      acc = __builtin_amdgcn_mfma_f32_16x16x32_bf16(a0, bfrag(FG2 + g*2 + 0), acc, 0, 0, 0);
      acc = __builtin_amdgcn_mfma_f32_16x16x32_bf16(a1, bfrag(FG2 + g*2 + 1), acc, 0, 0, 0);
      float cb = ws[CB_OFF_F + g * 16 + lo];
      acc[0] += cb; acc[1] += cb; acc[2] += cb; acc[3] += cb;
      cacc[g] = acc;
    }
  }

  __syncthreads();                 // all waves done reading XS (gate)
  st_tile<32, 136>(XS, tid, bufS); // write-late (vmcnt waits folded here)
  __syncthreads();

  // prefetch v tile while G3 computes
  float4 bufV[12];
  ld_tile<48>(xsp + 128, 480, baseRow, tid, bufV);

  // ---------- G3: s[16x16] ----------
  f32x4 sacc = {0.f, 0.f, 0.f, 0.f};
  {
    short8 a0 = afrag(0,136), a1 = afrag(1,136), a2 = afrag(2,136), a3 = afrag(3,136);
    sacc = __builtin_amdgcn_mfma_f32_16x16x32_bf16(a0, bfrag(FG3 + 0), sacc, 0, 0, 0);
    sacc = __builtin_amdgcn_mfma_f32_16x16x32_bf16(a1, bfrag(FG3 + 1), sacc, 0, 0, 0);
    sacc = __builtin_amdgcn_mfma_f32_16x16x32_bf16(a2, bfrag(FG3 + 2), sacc, 0, 0, 0);
    sacc = __builtin_amdgcn_mfma_f32_16x16x32_bf16(a3, bfrag(FG3 + 3), sacc, 0, 0, 0);
  }
  f32x4 P0 = {0,0,0,0};
#pragma unroll
  for (int r = 0; r < 4; ++r) {
    float s = sacc[r];
    P0[r] = fmaf(cacc[0][r] * s, s, P0[r]);   // c0*s^2
    cacc[3][r] *= s;                          // c3 -> c3*s
  }

  __syncthreads();                 // all waves done reading XS (s)
  st_tile<48, 200>(XS, tid, bufV);
  __syncthreads();

  // ---------- G4: v[16x48] (3 tiles = components i) ----------
  f32x4 vacc[3];
  {
    short8 a[6];
#pragma unroll
    for (int kk = 0; kk < 6; ++kk) a[kk] = afrag(kk, 200);
#pragma unroll
    for (int i = 0; i < 3; ++i) {
      f32x4 acc = {0.f, 0.f, 0.f, 0.f};
#pragma unroll
      for (int kk = 0; kk < 6; ++kk)
        acc = __builtin_amdgcn_mfma_f32_16x16x32_bf16(a[kk], bfrag(FG4 + i*6 + kk), acc, 0, 0, 0);
      vacc[i] = acc;
    }
  }
  f32x4 Q0 = {0,0,0,0}, Q1 = {0,0,0,0}, Q2 = {0,0,0,0}, Q3 = {0,0,0,0}, Q4 = {0,0,0,0};
#pragma unroll
  for (int r = 0; r < 4; ++r) {
    float a = vacc[0][r], b = vacc[1][r], d = vacc[2][r];
    float nv = fmaf(a, a, fmaf(b, b, d * d));
    P0[r] = fmaf(cacc[1][r], nv, P0[r]);                     // c1*|v|^2
    float c4h = cacc[4][r];
    Q0[r] = fmaf(c4h, SQ2 * d * a, Q0[r]);
    Q1[r] = fmaf(c4h, SQ2 * a * b, Q1[r]);
    Q2[r] = fmaf(c4h, (2.f*b*b - d*d - a*a) * I6, Q2[r]);
    Q3[r] = fmaf(c4h, SQ2 * b * d, Q3[r]);
    Q4[r] = fmaf(c4h, (d*d - a*a) * I2, Q4[r]);
  }

  __syncthreads();                 // all waves done reading XS (v)
  stage_sync<40, 168>(xsp + 320, 480, baseRow, tid, XS);
  __syncthreads();

  // ---------- G5: t5[16x80] (5 tiles = components m) ----------
  f32x4 tacc[5];
  {
    short8 a[5];
#pragma unroll
    for (int kk = 0; kk < 5; ++kk) a[kk] = afrag(kk, 168);
#pragma unroll
    for (int m = 0; m < 5; ++m) {
      f32x4 acc = {0.f, 0.f, 0.f, 0.f};
#pragma unroll
      for (int kk = 0; kk < 5; ++kk)
        acc = __builtin_amdgcn_mfma_f32_16x16x32_bf16(a[kk], bfrag(FG5 + m*5 + kk), acc, 0, 0, 0);
      tacc[m] = acc;
    }
  }
#pragma unroll
  for (int r = 0; r < 4; ++r) {
    float q0 = tacc[0][r], q1 = tacc[1][r], q2 = tacc[2][r], q3 = tacc[3][r], q4 = tacc[4][r];
    float nt = fmaf(q0,q0, fmaf(q1,q1, fmaf(q2,q2, fmaf(q3,q3, q4*q4))));
    P0[r] = fmaf(cacc[2][r], nt, P0[r]);                     // c2*|t|^2
    float c3s = cacc[3][r];
    Q0[r] = fmaf(c3s, q0, Q0[r]);
    Q1[r] = fmaf(c3s, q1, Q1[r]);
    Q2[r] = fmaf(c3s, q2, Q2[r]);
    Q3[r] = fmaf(c3s, q3, Q3[r]);
    Q4[r] = fmaf(c3s, q4, Q4[r]);
    float d0 = -q2*I6 - q4*I2;
    float d1 =  2.f*q2*I6;
    float d2 = -q2*I6 + q4*I2;
    float a = q1*I2, b = q0*I2, cc = q3*I2;
    float A00 = fmaf(d0,d0, fmaf(a,a, b*b));
    float A11 = fmaf(a,a, fmaf(d1,d1, cc*cc));
    float A22 = fmaf(b,b, fmaf(cc,cc, d2*d2));
    float A01 = fmaf(a, d0 + d1, b*cc);
    float A02 = fmaf(b, d0 + d2, a*cc);
    float A12 = fmaf(cc, d1 + d2, a*b);
    float c5h = cacc[5][r];
    Q0[r] = fmaf(c5h, SQ2 * A02, Q0[r]);
    Q1[r] = fmaf(c5h, SQ2 * A01, Q1[r]);
    Q2[r] = fmaf(c5h, (2.f*A11 - A22 - A00) * I6, Q2[r]);
    Q3[r] = fmaf(c5h, SQ2 * A12, Q3[r]);
    Q4[r] = fmaf(c5h, (A22 - A00) * I2, Q4[r]);
  }

  // ---------- reduce over 16 h-lanes, segment accumulate ----------
  float* __restrict__ ACC = ws + ACC_OFF;
  int gmin = bidx[blk * 64];
#pragma unroll
  for (int r = 0; r < 4; ++r) {
    float z0 = P0[r], z1 = Q0[r], z2 = Q1[r], z3 = Q2[r], z4 = Q3[r], z5 = Q4[r];
#pragma unroll
    for (int d = 1; d < 16; d <<= 1) {
      z0 += __shfl_xor(z0, d); z1 += __shfl_xor(z1, d); z2 += __shfl_xor(z2, d);
      z3 += __shfl_xor(z3, d); z4 += __shfl_xor(z4, d); z5 += __shfl_xor(z5, d);
    }
    if (lo == 0) {
      int node = blk * 64 + w * 16 + hi * 4 + r;
      int g = bidx[node];
      int rel = g - gmin;
      if (rel < SPAN) {
        atomicAdd(&accL[rel*6 + 0], z0); atomicAdd(&accL[rel*6 + 1], z1);
        atomicAdd(&accL[rel*6 + 2], z2); atomicAdd(&accL[rel*6 + 3], z3);
        atomicAdd(&accL[rel*6 + 4], z4); atomicAdd(&accL[rel*6 + 5], z5);
      } else {
        atomicAdd(&ACC[g*6 + 0], z0); atomicAdd(&ACC[g*6 + 1], z1);
        atomicAdd(&ACC[g*6 + 2], z2); atomicAdd(&ACC[g*6 + 3], z3);
        atomicAdd(&ACC[g*6 + 4], z4); atomicAdd(&ACC[g*6 + 5], z5);
      }
    }
  }
  __syncthreads();
  for (int i = tid; i < SPAN * 6; i += TPB) {
    float val = accL[i];
    if (val != 0.f) atomicAdd(&ACC[gmin * 6 + i], val);
  }
}

__global__ __launch_bounds__(64) void finalize_kernel(
    const float* __restrict__ ws, float* __restrict__ out)
{
  int g = blockIdx.x * 64 + threadIdx.x;
  if (g >= G_GRP) return;
  const float I2 = 0.70710678118f, I3 = 0.57735026919f, I6 = 0.40824829046f;
  const float* A = ws + ACC_OFF + g * 6;
  float g0 = A[0], q0 = A[1], q1 = A[2], q2 = A[3], q3 = A[4], q4 = A[5];
  float M00 = g0*I3 - q2*I6 - q4*I2;
  float M11 = g0*I3 + 2.f*q2*I6;
  float M22 = g0*I3 - q2*I6 + q4*I2;
  float M01 = q1*I2, M02 = q0*I2, M12 = q3*I2;
  float* o = out + g * 9;
  o[0] = M22; o[1] = M02; o[2] = M12;
  o[3] = M02; o[4] = M00; o[5] = M01;
  o[6] = M12; o[7] = M01; o[8] = M11;
}

extern "C" void kernel_launch(void* const* d_in, const int* in_sizes, int n_in,
                              void* d_out, int out_size, void* d_ws, size_t ws_size,
                              hipStream_t stream)
{
  const float* xsc = (const float*)d_in[0];
  const float* xsp = (const float*)d_in[1];
  const int*   bidx = (const int*)d_in[3];
  const float* W0  = (const float*)d_in[4];
  const float* W1  = (const float*)d_in[5];
  const float* W2  = (const float*)d_in[6];
  const float* Wg1 = (const float*)d_in[7];
  const float* bg1 = (const float*)d_in[8];
  const float* Wg2 = (const float*)d_in[9];
  const float* bg2 = (const float*)d_in[10];
  const float* wp0 = (const float*)d_in[11];
  const float* wp2 = (const float*)d_in[12];
  float* ws = (float*)d_ws;

  repack_kernel<<<151, 256, 0, stream>>>(W0, W1, W2, Wg1, bg1, Wg2, bg2, wp0, wp2, ws);
  node_kernel<<<N_NODES / NPB, TPB, 0, stream>>>(xsc, xsp, bidx, ws);
  finalize_kernel<<<(G_GRP + 63) / 64, 64, 0, stream>>>(ws, (float*)d_out);
}